// Round 13
// baseline (212.030 us; speedup 1.0000x reference)
//
#include <hip/hip_runtime.h>
#include <hip/hip_bf16.h>

// ---------------------------------------------------------------------------
// AttentionHead B=4,S=2048,D=1024 — all-f16 pipeline, round 13.
// gemm32 (new): r12's gemmO structure (256x128, BK=32, 3-deep, 72KiB LDS,
//   2 blocks/CU, counted vmcnt(3)) but with mfma_f32_32x32x16_f16:
//   half the MFMA instructions per FLOP, +15% measured ceiling (2495 vs 2176).
//   Wave tile 64x64 = 2x2 of 32x32; 8 ds_read + 8 MFMA per K-tile.
//   Swizzle: phys_chunk = (2*kk + (lane>>5)) ^ ((row>>1)&3); staging side
//   unchanged from r12 (proven conflict-free).
// prep: merged convert_x + transpose_conv_w (one launch fewer).
// ws (MiB): XF@0(48) WT@48(6) PROJ@54(48) VT@102(16) SC@118(32,f16)
//           P@0(32,f16, alias XF). high-water 150 MiB.
// ---------------------------------------------------------------------------

typedef __attribute__((ext_vector_type(4)))  float    f32x4;
typedef __attribute__((ext_vector_type(16))) float    f32x16;
typedef __attribute__((ext_vector_type(8)))  _Float16 f16x8;
typedef __attribute__((ext_vector_type(4)))  _Float16 f16x4;

constexpr size_t MiB = 1u << 20;
constexpr size_t MK  = (size_t)8192 * 1024;
constexpr size_t WSZ = (size_t)1024 * 1024;

__device__ __forceinline__ void gload_lds16(const void* g, void* l) {
  __builtin_amdgcn_global_load_lds(
      (const __attribute__((address_space(1))) unsigned int*)g,
      (__attribute__((address_space(3))) unsigned int*)l, 16, 0, 0);
}

#define MFMA32(a, b, c) __builtin_amdgcn_mfma_f32_32x32x16_f16(a, b, c, 0, 0, 0)

// XCD-chunked bijective block swizzle (requires total blocks % 8 == 0).
__device__ __forceinline__ void swz_block(int& bx, int& by, int& bz) {
  unsigned gx = gridDim.x, gy = gridDim.y;
  unsigned flat = blockIdx.x + gx * (blockIdx.y + gy * blockIdx.z);
  unsigned total = gx * gy * gridDim.z;
  unsigned cpx = total >> 3;
  unsigned s = (flat & 7) * cpx + (flat >> 3);
  bx = s % gx; s /= gx; by = s % gy; bz = s / gy;
}

// ---------------------------------------------------------------------------
// prep: merged X->f16 convert (ids 0..24575) + W->W^T f16 (ids 24576..27647).
__global__ __launch_bounds__(256) void prep(
    const float* __restrict__ x0, const float* __restrict__ x1,
    const float* __restrict__ x2, _Float16* __restrict__ XF,
    const float* __restrict__ w0, const float* __restrict__ w1,
    const float* __restrict__ w2, _Float16* __restrict__ WT)
{
  const unsigned id = blockIdx.x;
  if (id < 24576) {
    const int z = id >> 13;              // id / 8192
    const unsigned blk = id & 8191;
    const float* x = z == 0 ? x0 : (z == 1 ? x1 : x2);
    size_t i = ((size_t)blk * 256 + threadIdx.x) * 4;
    float4 v = *(const float4*)(x + i);
    f16x4 h = {(_Float16)v.x, (_Float16)v.y, (_Float16)v.z, (_Float16)v.w};
    *(f16x4*)(XF + (size_t)z * MK + i) = h;
  } else {
    const unsigned rem = id - 24576;
    const int z = rem >> 10;             // rem / 1024
    const unsigned blk = rem & 1023;
    const float* W = z == 0 ? w0 : (z == 1 ? w1 : w2);
    _Float16* o = WT + (size_t)z * WSZ;
    __shared__ float tile[32][33];
    const int bx = (blk & 31) * 32;
    const int by = (blk >> 5) * 32;
    const int tx = threadIdx.x & 31, ty = threadIdx.x >> 5;
    #pragma unroll
    for (int r = 0; r < 32; r += 8)
      tile[ty + r][tx] = W[(size_t)(by + ty + r) * 1024 + bx + tx];
    __syncthreads();
    #pragma unroll
    for (int r = 0; r < 32; r += 8)
      o[(size_t)(bx + ty + r) * 1024 + by + tx] = (_Float16)tile[tx][ty + r];
  }
}

// ---------------------------------------------------------------------------
__global__ __launch_bounds__(256) void transpose_v(
    const _Float16* __restrict__ V, _Float16* __restrict__ Vt)
{
  const _Float16* v = V + (size_t)blockIdx.z * 2048 * 1024;
  _Float16* o = Vt + (size_t)blockIdx.z * 1024 * 2048;
  __shared__ _Float16 tile[32][33];
  const int bx = blockIdx.x * 32;   // e
  const int by = blockIdx.y * 32;   // s
  const int tx = threadIdx.x & 31, ty = threadIdx.x >> 5;
  #pragma unroll
  for (int r = 0; r < 32; r += 8)
    tile[ty + r][tx] = v[(size_t)(by + ty + r) * 1024 + bx + tx];
  __syncthreads();
  #pragma unroll
  for (int r = 0; r < 32; r += 8)
    o[(size_t)(bx + ty + r) * 2048 + by + tx] = tile[tx][ty + r];
}

// ---------------------------------------------------------------------------
// gemm32: 256(M)x128(N), BK=32, 512 thr = 8 waves (4M x 2N, wave 64x64 as
// 2x2 of 32x32 MFMA). 3-deep pipeline, 3 x 24 KiB LDS buffers
// (A 16K @0, B 8K @16384 per buf) -> 72 KiB -> 2 blocks/CU.
// Stage tile t+2 during t (3 gloads); boundary vmcnt(3) steady, 0 tail.
// Staging swizzle identical to r12 (proven conflict-free):
//   LDS row t>>2, phys chunk t&3, logical chunk = (t&3)^((row>>1)&3).
// Fragment reads: lane row r5 = wm/wn + tile*32 + (lane&31);
//   phys chunk = (2*kk + (lane>>5)) ^ ((r5>>1)&3)  [2 lanes/chunk per
//   16-lane quarter -> free].
// A-frag layout (32x32x16 f16): row = lane&31, k = (lane>>5)*8 + i.
// C/D: col = lane&31, row = (reg&3) + 8*(reg>>2) + 4*(lane>>5).
// MODE 0: f32*scale ; 1: f16 ; 2: f16*scale.
template <int MODE>
__global__ __launch_bounds__(512, 4) void gemm32(
    const _Float16* __restrict__ At, size_t sA,
    const _Float16* __restrict__ Bt, size_t sB,
    void* __restrict__ Cv, size_t sCz,
    int N, int K, float scale)
{
  extern __shared__ char lds[];
  int bx, by, bz;
  swz_block(bx, by, bz);
  const _Float16* A = At + (size_t)bz * sA;
  const _Float16* B = Bt + (size_t)bz * sB;

  const int gm0 = by * 256, gn0 = bx * 128;
  const int tid = threadIdx.x;
  const int lane = tid & 63, wave = tid >> 6;
  const int wm = (wave >> 1) * 64;    // 4 M groups of 64
  const int wn = (wave & 1) * 64;     // 2 N groups of 64
  const int r5 = lane & 31;           // row within 32-tile
  const int hh = lane >> 5;           // k-half selector
  const int nkt = K >> 5;

  // staging (identical to r12): thread t -> LDS row t>>2, phys chunk t&3
  const int clog = ((tid & 3) ^ ((tid >> 3) & 3)) * 8;   // element offset
  const _Float16* srcA = A + (size_t)(gm0 + (tid >> 2)) * K + clog;
  const _Float16* srcB = B + (size_t)(gn0 + (tid >> 2)) * K + clog;
  char* const dst0 = lds + tid * 16;

  auto STG = [&](int tile) {
    const int off = tile * 32;
    char* d = dst0 + (tile % 3) * 24576;
    gload_lds16(srcA + off,                   d);
    gload_lds16(srcA + off + (size_t)128 * K, d + 8192);
    gload_lds16(srcB + off,                   d + 16384);
  };

  // fragment read chunk bytes: pc[kk] = ((2*kk + hh) ^ ((r5>>1)&3)) * 16
  const int rx = (r5 >> 1) & 3;
  const int pc0 = ((0 + hh) ^ rx) * 16;
  const int pc1 = ((2 + hh) ^ rx) * 16;
  // row base bytes (row stride 64B)
  const int ar0 = (wm + r5) * 64;            // A m-tile 0
  const int ar1 = (wm + 32 + r5) * 64;       // A m-tile 1
  const int br0 = 16384 + (wn + r5) * 64;    // B n-tile 0
  const int br1 = 16384 + (wn + 32 + r5) * 64;

  f32x16 acc[2][2] = {};
  f16x8 a0k0, a0k1, a1k0, a1k1, b0k0, b0k1, b1k0, b1k1;

  // prologue: stage tiles 0,1 (6 loads); wait tile 0 (vmcnt 3)
  STG(0);
  if (nkt > 1) {
    STG(1);
    asm volatile("s_waitcnt vmcnt(3)" ::: "memory");
  } else {
    asm volatile("s_waitcnt vmcnt(0)" ::: "memory");
  }
  __builtin_amdgcn_s_barrier();
  __builtin_amdgcn_sched_barrier(0);

  for (int t = 0; t < nkt; ++t) {
    const char* buf = lds + (t % 3) * 24576;
    const bool st2 = (t + 2) < nkt;

    if (st2) STG(t + 2);   // buffer (t+2)%3 freed by iter t-1's barrier

    a0k0 = *(const f16x8*)(buf + ar0 + pc0);
    a0k1 = *(const f16x8*)(buf + ar0 + pc1);
    a1k0 = *(const f16x8*)(buf + ar1 + pc0);
    a1k1 = *(const f16x8*)(buf + ar1 + pc1);
    b0k0 = *(const f16x8*)(buf + br0 + pc0);
    b0k1 = *(const f16x8*)(buf + br0 + pc1);
    b1k0 = *(const f16x8*)(buf + br1 + pc0);
    b1k1 = *(const f16x8*)(buf + br1 + pc1);

    __builtin_amdgcn_s_setprio(1);
    acc[0][0] = MFMA32(a0k0, b0k0, acc[0][0]);
    acc[0][1] = MFMA32(a0k0, b1k0, acc[0][1]);
    acc[1][0] = MFMA32(a1k0, b0k0, acc[1][0]);
    acc[1][1] = MFMA32(a1k0, b1k0, acc[1][1]);
    acc[0][0] = MFMA32(a0k1, b0k1, acc[0][0]);
    acc[0][1] = MFMA32(a0k1, b1k1, acc[0][1]);
    acc[1][0] = MFMA32(a1k1, b0k1, acc[1][0]);
    acc[1][1] = MFMA32(a1k1, b1k1, acc[1][1]);
    __builtin_amdgcn_s_setprio(0);

    // boundary: tile t+1 must have landed; t+2's 3 loads may stay in flight
    if (st2)               asm volatile("s_waitcnt vmcnt(3)" ::: "memory");
    else if (t + 1 < nkt)  asm volatile("s_waitcnt vmcnt(0)" ::: "memory");
    __builtin_amdgcn_s_barrier();
    __builtin_amdgcn_sched_barrier(0);
  }

  // epilogue: C/D col = lane&31, row = (reg&3) + 8*(reg>>2) + 4*hh
  #pragma unroll
  for (int mi = 0; mi < 2; ++mi)
    #pragma unroll
    for (int ni = 0; ni < 2; ++ni) {
      const int colg = gn0 + wn + ni * 32 + r5;
      #pragma unroll
      for (int reg = 0; reg < 16; ++reg) {
        const int rowg = gm0 + wm + mi * 32 + (reg & 3) + 8 * (reg >> 2) + 4 * hh;
        const float v = acc[mi][ni][reg];
        const size_t idx = (size_t)rowg * N + colg;
        if constexpr (MODE == 0)
          ((float*)Cv + (size_t)bz * sCz)[idx] = v * scale;
        else if constexpr (MODE == 1)
          ((_Float16*)Cv + (size_t)bz * sCz)[idx] = (_Float16)v;
        else
          ((_Float16*)Cv + (size_t)bz * sCz)[idx] = (_Float16)(v * scale);
      }
    }
}

// ---------------------------------------------------------------------------
// Wave-per-row softmax: scores [8192 rows][2048] f16 -> P f16. 4 rows/block.
__global__ __launch_bounds__(256) void softmax_rows(
    const _Float16* __restrict__ S, _Float16* __restrict__ P)
{
  const int w = threadIdx.x >> 6, lane = threadIdx.x & 63;
  const size_t row = (size_t)blockIdx.x * 4 + w;
  const _Float16* sr = S + row * 2048;

  f16x8 v[4];
  #pragma unroll
  for (int c = 0; c < 4; ++c)
    v[c] = *(const f16x8*)(sr + c * 512 + lane * 8);

  float m = -1e30f;
  #pragma unroll
  for (int c = 0; c < 4; ++c)
    #pragma unroll
    for (int j = 0; j < 8; ++j) m = fmaxf(m, (float)v[c][j]);
  #pragma unroll
  for (int o = 32; o >= 1; o >>= 1) m = fmaxf(m, __shfl_xor(m, o));

  float e[4][8];
  float s = 0.f;
  #pragma unroll
  for (int c = 0; c < 4; ++c)
    #pragma unroll
    for (int j = 0; j < 8; ++j) {
      e[c][j] = __expf((float)v[c][j] - m);
      s += e[c][j];
    }
  #pragma unroll
  for (int o = 32; o >= 1; o >>= 1) s += __shfl_xor(s, o);

  const float inv = 1.0f / s;
  _Float16* pr = P + row * 2048;
  #pragma unroll
  for (int c = 0; c < 4; ++c) {
    f16x8 p;
    #pragma unroll
    for (int j = 0; j < 8; ++j) p[j] = (_Float16)(e[c][j] * inv);
    *(f16x8*)(pr + c * 512 + lane * 8) = p;
  }
}

// ---------------------------------------------------------------------------
extern "C" void kernel_launch(void* const* d_in, const int* in_sizes, int n_in,
                              void* d_out, int out_size, void* d_ws, size_t ws_size,
                              hipStream_t stream)
{
  const float* Xk = (const float*)d_in[0];
  const float* Xv = (const float*)d_in[1];
  const float* Xq = (const float*)d_in[2];
  const float* WK = (const float*)d_in[3];
  const float* WV = (const float*)d_in[4];
  const float* WQ = (const float*)d_in[5];
  float* out = (float*)d_out;
  char* ws = (char*)d_ws;

  _Float16* XF   = (_Float16*)(ws);               // 0..48 MiB
  _Float16* WT   = (_Float16*)(ws + 48 * MiB);    // 48..54
  _Float16* PROJ = (_Float16*)(ws + 54 * MiB);    // 54..102 (K,V,Q)
  _Float16* VT   = (_Float16*)(ws + 102 * MiB);   // 102..118
  _Float16* SC   = (_Float16*)(ws + 118 * MiB);   // 118..150 (f16 scores)
  _Float16* P    = (_Float16*)(ws);               // alias XF (dead post-proj)

  _Float16* Kp = PROJ;
  _Float16* Vp = PROJ + MK;
  _Float16* Qp = PROJ + 2 * MK;

  auto* fP  = gemm32<1>;
  auto* fSC = gemm32<2>;
  auto* fPV = gemm32<0>;
  (void)hipFuncSetAttribute((const void*)fP,  hipFuncAttributeMaxDynamicSharedMemorySize, 73728);
  (void)hipFuncSetAttribute((const void*)fSC, hipFuncAttributeMaxDynamicSharedMemorySize, 73728);
  (void)hipFuncSetAttribute((const void*)fPV, hipFuncAttributeMaxDynamicSharedMemorySize, 73728);

  // 1) merged: X -> f16 (k,v,q) + W -> W^T f16 (K,V,Q)
  prep<<<dim3(27648), 256, 0, stream>>>(Xk, Xv, Xq, XF, WK, WV, WQ, WT);
  // 2) projections: PROJ[z] = XF[z] @ WT[z]^T  (M=8192,N=1024,K=1024)
  //    768 blocks @ 2 blocks/CU
  gemm32<1><<<dim3(8, 32, 3), 512, 73728, stream>>>(
      XF, MK, WT, WSZ, PROJ, MK, 1024, 1024, 1.0f);
  // 3) V^T per batch
  transpose_v<<<dim3(32, 64, 4), 256, 0, stream>>>(Vp, VT);
  // 4) scores[b] = Q[b]@K[b]^T / sqrt(2048) -> f16  (512 blocks)
  gemm32<2><<<dim3(16, 8, 4), 512, 73728, stream>>>(
      Qp, (size_t)2048 * 1024, Kp, (size_t)2048 * 1024,
      SC, (size_t)2048 * 2048, 2048, 1024, 0.022097086912079608f);
  // 5) softmax (wave-per-row) -> P f16
  softmax_rows<<<dim3(2048), 256, 0, stream>>>(SC, P);
  // 6) out[b] = P[b] @ VT[b]^T  (M=2048,N=1024,K=2048; 256 blocks)
  gemm32<0><<<dim3(8, 8, 4), 512, 73728, stream>>>(
      P, (size_t)2048 * 2048, VT, (size_t)1024 * 2048,
      out, (size_t)2048 * 1024, 1024, 2048, 1.0f);
}

// Round 14
// 195.321 us; speedup vs baseline: 1.0855x; 1.0855x over previous
//
#include <hip/hip_runtime.h>
#include <hip/hip_bf16.h>

// ---------------------------------------------------------------------------
// AttentionHead B=4,S=2048,D=1024 — all-f16 pipeline, round 14.
// Revert to r12's proven gemmO (16x16 MFMA, conflict-free swizzle, 3-deep,
// 2 blocks/CU). New: V^T produced DIRECTLY by projection (V^T = WVt @ Xv^T in
// bt-form: C[e][s] = sum_k WT_V[e][k] * Xv[s][k]) -> transpose_v eliminated.
// gemmO generalized with lda/ldb/ldc (PV reads VT_full with ldb=8192).
// ws (MiB): XF@0(48) WT@48(6) PROJ@54(32: K,Q) VTf@86(16) SC@102(32,f16)
//           P@0(32,f16, alias XF_k+XF_v, dead post-proj). high-water 134 MiB.
// ---------------------------------------------------------------------------

typedef __attribute__((ext_vector_type(4))) float    f32x4;
typedef __attribute__((ext_vector_type(8))) _Float16 f16x8;
typedef __attribute__((ext_vector_type(4))) _Float16 f16x4;

constexpr size_t MiB = 1u << 20;
constexpr size_t MK  = (size_t)8192 * 1024;
constexpr size_t WSZ = (size_t)1024 * 1024;

__device__ __forceinline__ void gload_lds16(const void* g, void* l) {
  __builtin_amdgcn_global_load_lds(
      (const __attribute__((address_space(1))) unsigned int*)g,
      (__attribute__((address_space(3))) unsigned int*)l, 16, 0, 0);
}

#define MFMA16(a, b, c) __builtin_amdgcn_mfma_f32_16x16x32_f16(a, b, c, 0, 0, 0)

// XCD-chunked bijective block swizzle (requires total blocks % 8 == 0).
__device__ __forceinline__ void swz_block(int& bx, int& by, int& bz) {
  unsigned gx = gridDim.x, gy = gridDim.y;
  unsigned flat = blockIdx.x + gx * (blockIdx.y + gy * blockIdx.z);
  unsigned total = gx * gy * gridDim.z;
  unsigned cpx = total >> 3;
  unsigned s = (flat & 7) * cpx + (flat >> 3);
  bx = s % gx; s /= gx; by = s % gy; bz = s / gy;
}

// ---------------------------------------------------------------------------
// prep: merged X->f16 convert (ids 0..24575) + W->W^T f16 (ids 24576..27647).
__global__ __launch_bounds__(256) void prep(
    const float* __restrict__ x0, const float* __restrict__ x1,
    const float* __restrict__ x2, _Float16* __restrict__ XF,
    const float* __restrict__ w0, const float* __restrict__ w1,
    const float* __restrict__ w2, _Float16* __restrict__ WT)
{
  const unsigned id = blockIdx.x;
  if (id < 24576) {
    const int z = id >> 13;
    const unsigned blk = id & 8191;
    const float* x = z == 0 ? x0 : (z == 1 ? x1 : x2);
    size_t i = ((size_t)blk * 256 + threadIdx.x) * 4;
    float4 v = *(const float4*)(x + i);
    f16x4 h = {(_Float16)v.x, (_Float16)v.y, (_Float16)v.z, (_Float16)v.w};
    *(f16x4*)(XF + (size_t)z * MK + i) = h;
  } else {
    const unsigned rem = id - 24576;
    const int z = rem >> 10;
    const unsigned blk = rem & 1023;
    const float* W = z == 0 ? w0 : (z == 1 ? w1 : w2);
    _Float16* o = WT + (size_t)z * WSZ;
    __shared__ float tile[32][33];
    const int bx = (blk & 31) * 32;
    const int by = (blk >> 5) * 32;
    const int tx = threadIdx.x & 31, ty = threadIdx.x >> 5;
    #pragma unroll
    for (int r = 0; r < 32; r += 8)
      tile[ty + r][tx] = W[(size_t)(by + ty + r) * 1024 + bx + tx];
    __syncthreads();
    #pragma unroll
    for (int r = 0; r < 32; r += 8)
      o[(size_t)(bx + ty + r) * 1024 + by + tx] = (_Float16)tile[tx][ty + r];
  }
}

// ---------------------------------------------------------------------------
// gemmO (r12 proven, + lda/ldb/ldc): C[m][n] = scale * sum_k A[m][k]*B[n][k].
// 256(M)x128(N), BK=32, 512 thr = 8 waves (4M x 2N, wave 64x64).
// 3-deep pipeline, 3 x 24 KiB LDS buffers -> 72 KiB -> 2 blocks/CU.
// Stage tile t+2 during t (3 gloads); boundary vmcnt(3) steady, 0 tail.
// Swizzle: phys_chunk = logical ^ ((row>>1)&3) (conflict-free, measured r12),
// applied source-side (staging) + read-side.
// MODE 0: f32*scale ; 1: f16 ; 2: f16*scale.
template <int MODE>
__global__ __launch_bounds__(512, 4) void gemmO(
    const _Float16* __restrict__ At, size_t sAz, int lda,
    const _Float16* __restrict__ Bt, size_t sBz, int ldb,
    void* __restrict__ Cv, size_t sCz, int ldc,
    int K, float scale)
{
  extern __shared__ char lds[];
  int bx, by, bz;
  swz_block(bx, by, bz);
  const _Float16* A = At + (size_t)bz * sAz;
  const _Float16* B = Bt + (size_t)bz * sBz;

  const int gm0 = by * 256, gn0 = bx * 128;
  const int tid = threadIdx.x;
  const int lane = tid & 63, wave = tid >> 6;
  const int wm = (wave >> 1) * 64;    // 4 M groups of 64
  const int wn = (wave & 1) * 64;     // 2 N groups of 64
  const int fr = lane & 15, fq = lane >> 4;
  const int nkt = K >> 5;

  // staging: thread t -> LDS row t>>2, phys chunk t&3
  // -> global logical chunk = (t&3) ^ ((row>>1)&3) = (t&3) ^ ((t>>3)&3)
  const int clog = ((tid & 3) ^ ((tid >> 3) & 3)) * 8;   // element offset
  const _Float16* srcA = A + (size_t)(gm0 + (tid >> 2)) * lda + clog;
  const _Float16* srcB = B + (size_t)(gn0 + (tid >> 2)) * ldb + clog;
  char* const dst0 = lds + tid * 16;

  auto STG = [&](int tile) {
    const int off = tile * 32;
    char* d = dst0 + (tile % 3) * 24576;
    gload_lds16(srcA + off,                     d);
    gload_lds16(srcA + off + (size_t)128 * lda, d + 8192);
    gload_lds16(srcB + off,                     d + 16384);
  };

  // fragment reads (swizzled): row stride 64B; pc = (fq ^ ((fr>>1)&3))*16
  const int pc  = (fq ^ ((fr >> 1) & 3)) * 16;
  const int arb = (wm + fr) * 64 + pc;
  const int brb = 16384 + (wn + fr) * 64 + pc;

  f32x4 acc[4][4] = {};
  f16x8 af[4], bfr[4];

  // prologue: stage tiles 0,1 (6 loads); wait tile 0 (vmcnt 3)
  STG(0);
  if (nkt > 1) {
    STG(1);
    asm volatile("s_waitcnt vmcnt(3)" ::: "memory");
  } else {
    asm volatile("s_waitcnt vmcnt(0)" ::: "memory");
  }
  __builtin_amdgcn_s_barrier();
  __builtin_amdgcn_sched_barrier(0);

  for (int t = 0; t < nkt; ++t) {
    const char* buf = lds + (t % 3) * 24576;
    const bool st2 = (t + 2) < nkt;

    if (st2) STG(t + 2);   // buffer (t+2)%3 freed by iter t-1's barrier

    #pragma unroll
    for (int mi = 0; mi < 4; ++mi)
      af[mi] = *(const f16x8*)(buf + arb + mi * 1024);
    #pragma unroll
    for (int ni = 0; ni < 4; ++ni)
      bfr[ni] = *(const f16x8*)(buf + brb + ni * 1024);

    __builtin_amdgcn_s_setprio(1);
    #pragma unroll
    for (int mi = 0; mi < 4; ++mi)
      #pragma unroll
      for (int ni = 0; ni < 4; ++ni)
        acc[mi][ni] = MFMA16(af[mi], bfr[ni], acc[mi][ni]);
    __builtin_amdgcn_s_setprio(0);

    // boundary: tile t+1 must have landed; t+2's 3 loads may stay in flight
    if (st2)               asm volatile("s_waitcnt vmcnt(3)" ::: "memory");
    else if (t + 1 < nkt)  asm volatile("s_waitcnt vmcnt(0)" ::: "memory");
    __builtin_amdgcn_s_barrier();
    __builtin_amdgcn_sched_barrier(0);
  }

  // epilogue: C/D layout col=fr, row=fq*4+r
  const int erow = gm0 + wm + fq * 4;
  const int ecol = gn0 + wn + fr;
  #pragma unroll
  for (int m = 0; m < 4; ++m)
    #pragma unroll
    for (int n = 0; n < 4; ++n) {
      size_t base = (size_t)(erow + m * 16) * ldc + (ecol + n * 16);
      #pragma unroll
      for (int r = 0; r < 4; ++r) {
        float v = acc[m][n][r];
        size_t idx = base + (size_t)r * ldc;
        if constexpr (MODE == 0)
          ((float*)Cv + (size_t)bz * sCz)[idx] = v * scale;
        else if constexpr (MODE == 1)
          ((_Float16*)Cv + (size_t)bz * sCz)[idx] = (_Float16)v;
        else
          ((_Float16*)Cv + (size_t)bz * sCz)[idx] = (_Float16)(v * scale);
      }
    }
}

// ---------------------------------------------------------------------------
// Wave-per-row softmax: scores [8192 rows][2048] f16 -> P f16. 4 rows/block.
__global__ __launch_bounds__(256) void softmax_rows(
    const _Float16* __restrict__ S, _Float16* __restrict__ P)
{
  const int w = threadIdx.x >> 6, lane = threadIdx.x & 63;
  const size_t row = (size_t)blockIdx.x * 4 + w;
  const _Float16* sr = S + row * 2048;

  f16x8 v[4];
  #pragma unroll
  for (int c = 0; c < 4; ++c)
    v[c] = *(const f16x8*)(sr + c * 512 + lane * 8);

  float m = -1e30f;
  #pragma unroll
  for (int c = 0; c < 4; ++c)
    #pragma unroll
    for (int j = 0; j < 8; ++j) m = fmaxf(m, (float)v[c][j]);
  #pragma unroll
  for (int o = 32; o >= 1; o >>= 1) m = fmaxf(m, __shfl_xor(m, o));

  float e[4][8];
  float s = 0.f;
  #pragma unroll
  for (int c = 0; c < 4; ++c)
    #pragma unroll
    for (int j = 0; j < 8; ++j) {
      e[c][j] = __expf((float)v[c][j] - m);
      s += e[c][j];
    }
  #pragma unroll
  for (int o = 32; o >= 1; o >>= 1) s += __shfl_xor(s, o);

  const float inv = 1.0f / s;
  _Float16* pr = P + row * 2048;
  #pragma unroll
  for (int c = 0; c < 4; ++c) {
    f16x8 p;
    #pragma unroll
    for (int j = 0; j < 8; ++j) p[j] = (_Float16)(e[c][j] * inv);
    *(f16x8*)(pr + c * 512 + lane * 8) = p;
  }
}

// ---------------------------------------------------------------------------
extern "C" void kernel_launch(void* const* d_in, const int* in_sizes, int n_in,
                              void* d_out, int out_size, void* d_ws, size_t ws_size,
                              hipStream_t stream)
{
  const float* Xk = (const float*)d_in[0];
  const float* Xv = (const float*)d_in[1];
  const float* Xq = (const float*)d_in[2];
  const float* WK = (const float*)d_in[3];
  const float* WV = (const float*)d_in[4];
  const float* WQ = (const float*)d_in[5];
  float* out = (float*)d_out;
  char* ws = (char*)d_ws;

  _Float16* XF   = (_Float16*)(ws);               // 0..48 MiB (k,v,q)
  _Float16* WT   = (_Float16*)(ws + 48 * MiB);    // 48..54 (K,V,Q)
  _Float16* PROJ = (_Float16*)(ws + 54 * MiB);    // 54..86 (K,Q)
  _Float16* VTf  = (_Float16*)(ws + 86 * MiB);    // 86..102 [1024][8192]
  _Float16* SC   = (_Float16*)(ws + 102 * MiB);   // 102..134 (f16 scores)
  _Float16* P    = (_Float16*)(ws);               // alias XF_k+XF_v

  _Float16* Kp = PROJ;            // [8192][1024]
  _Float16* Qp = PROJ + MK;       // [8192][1024]

  auto* f1 = gemmO<1>;
  auto* f2 = gemmO<2>;
  auto* f0 = gemmO<0>;
  (void)hipFuncSetAttribute((const void*)f1, hipFuncAttributeMaxDynamicSharedMemorySize, 73728);
  (void)hipFuncSetAttribute((const void*)f2, hipFuncAttributeMaxDynamicSharedMemorySize, 73728);
  (void)hipFuncSetAttribute((const void*)f0, hipFuncAttributeMaxDynamicSharedMemorySize, 73728);

  // 1) merged: X -> f16 (k,v,q) + W -> W^T f16 (K,V,Q)
  prep<<<dim3(27648), 256, 0, stream>>>(Xk, Xv, Xq, XF, WK, WV, WQ, WT);
  // 2) K,Q projections: z=0 -> K (XF_k @ WT_K^T), z=1 -> Q (XF_q @ WT_Q^T)
  //    512 blocks = 2 exact rounds
  gemmO<1><<<dim3(8, 32, 2), 512, 73728, stream>>>(
      XF, 2 * MK, 1024, WT, 2 * WSZ, 1024,
      PROJ, MK, 1024, 1024, 1.0f);
  // 3) V^T projection: VTf[e][s_glob] = sum_k WT_V[e][k] * XF_v[s][k]
  //    (= V[s][e]); M=1024, N=8192 -> 256 blocks = 1 exact round
  gemmO<1><<<dim3(64, 4, 1), 512, 73728, stream>>>(
      WT + WSZ, 0, 1024, XF + MK, 0, 1024,
      VTf, 0, 8192, 1024, 1.0f);
  // 4) scores[b] = Q[b]@K[b]^T / sqrt(2048) -> f16  (512 blocks)
  gemmO<2><<<dim3(16, 8, 4), 512, 73728, stream>>>(
      Qp, (size_t)2048 * 1024, 1024, Kp, (size_t)2048 * 1024, 1024,
      SC, (size_t)2048 * 2048, 2048, 1024, 0.022097086912079608f);
  // 5) softmax (wave-per-row) -> P f16
  softmax_rows<<<dim3(2048), 256, 0, stream>>>(SC, P);
  // 6) out[b] = P[b] @ V[b]: C[m][e] = sum_k P[m][k] * VTf[e][b*2048+k]
  //    (256 blocks = 1 round; B batch-offset 2048 elems, ldb 8192)
  gemmO<0><<<dim3(8, 8, 4), 512, 73728, stream>>>(
      P, (size_t)2048 * 2048, 2048, VTf, 2048, 8192,
      out, (size_t)2048 * 1024, 1024, 2048, 1.0f);
}

// Round 15
// 182.982 us; speedup vs baseline: 1.1587x; 1.0674x over previous
//
#include <hip/hip_runtime.h>
#include <hip/hip_bf16.h>

// ---------------------------------------------------------------------------
// AttentionHead B=4,S=2048,D=1024 — all-f16 pipeline, round 15.
// Changes vs r14 (all from session-verified parts):
//  - prep: 16 floats/thread (was 4) -> ~2x BW (44 -> ~24 us predicted)
//  - KQ-proj & scores: r7's gemm8p (256x256 BK=64 4-phase, 947 TF in-round)
//    at exact-fill grids (256 blocks = 1.0 round each)
//  - VT-proj & PV: r14's gemmO (256x128, lda/ldb/ldc) unchanged
// ws (MiB): XF@0(48) WT@48(6) PROJ@54(32: K,Q) VTf@86(16) SC@102(32,f16)
//           P@0(32,f16, alias XF_k+XF_v). high-water 134 MiB.
// ---------------------------------------------------------------------------

typedef __attribute__((ext_vector_type(4))) float    f32x4;
typedef __attribute__((ext_vector_type(8))) _Float16 f16x8;
typedef __attribute__((ext_vector_type(4))) _Float16 f16x4;

constexpr size_t MiB = 1u << 20;
constexpr size_t MK  = (size_t)8192 * 1024;
constexpr size_t WSZ = (size_t)1024 * 1024;

__device__ __forceinline__ void gload_lds16(const void* g, void* l) {
  __builtin_amdgcn_global_load_lds(
      (const __attribute__((address_space(1))) unsigned int*)g,
      (__attribute__((address_space(3))) unsigned int*)l, 16, 0, 0);
}

#define MFMA16(a, b, c) __builtin_amdgcn_mfma_f32_16x16x32_f16(a, b, c, 0, 0, 0)

// XCD-chunked bijective block swizzle (requires total blocks % 8 == 0).
__device__ __forceinline__ void swz_block(int& bx, int& by, int& bz) {
  unsigned gx = gridDim.x, gy = gridDim.y;
  unsigned flat = blockIdx.x + gx * (blockIdx.y + gy * blockIdx.z);
  unsigned total = gx * gy * gridDim.z;
  unsigned cpx = total >> 3;
  unsigned s = (flat & 7) * cpx + (flat >> 3);
  bx = s % gx; s /= gx; by = s % gy; bz = s / gy;
}

// ---------------------------------------------------------------------------
// prep: X->f16 (ids 0..6143, 16 floats/thread) + W->W^T f16 (ids 6144..9215).
__global__ __launch_bounds__(256) void prep(
    const float* __restrict__ x0, const float* __restrict__ x1,
    const float* __restrict__ x2, _Float16* __restrict__ XF,
    const float* __restrict__ w0, const float* __restrict__ w1,
    const float* __restrict__ w2, _Float16* __restrict__ WT)
{
  const unsigned id = blockIdx.x;
  if (id < 6144) {
    const int z = id >> 11;              // 2048 blocks per matrix
    const unsigned blk = id & 2047;
    const float* x = (z == 0 ? x0 : (z == 1 ? x1 : x2)) + (size_t)blk * 4096;
    _Float16* o = XF + (size_t)z * MK + (size_t)blk * 4096;
    #pragma unroll
    for (int j = 0; j < 4; ++j) {
      size_t i = (size_t)j * 1024 + threadIdx.x * 4;
      float4 v = *(const float4*)(x + i);
      f16x4 h = {(_Float16)v.x, (_Float16)v.y, (_Float16)v.z, (_Float16)v.w};
      *(f16x4*)(o + i) = h;
    }
  } else {
    const unsigned rem = id - 6144;
    const int z = rem >> 10;
    const unsigned blk = rem & 1023;
    const float* W = z == 0 ? w0 : (z == 1 ? w1 : w2);
    _Float16* o = WT + (size_t)z * WSZ;
    __shared__ float tile[32][33];
    const int bx = (blk & 31) * 32;
    const int by = (blk >> 5) * 32;
    const int tx = threadIdx.x & 31, ty = threadIdx.x >> 5;
    #pragma unroll
    for (int r = 0; r < 32; r += 8)
      tile[ty + r][tx] = W[(size_t)(by + ty + r) * 1024 + bx + tx];
    __syncthreads();
    #pragma unroll
    for (int r = 0; r < 32; r += 8)
      o[(size_t)(bx + ty + r) * 1024 + by + tx] = (_Float16)tile[tx][ty + r];
  }
}

// ---------------------------------------------------------------------------
// gemm8p (r7 verbatim, session-verified): 256x256 BK=64, 4 phases/K-tile,
// 2x64KiB LDS dbuf, counted vmcnt(2), setprio, 8-chunk XOR swizzle.
// MODE 0: f32*scale ; 1: f16 ; 2: f16*scale.
template <int MODE>
__global__ __launch_bounds__(512, 2) void gemm8p(
    const _Float16* __restrict__ At, size_t sA,
    const _Float16* __restrict__ Bt, size_t sB,
    void* __restrict__ Cv, size_t sCz,
    int N, int K, float scale)
{
  extern __shared__ char lds[];
  int bx, by, bz;
  swz_block(bx, by, bz);
  const _Float16* A = At + (size_t)bz * sA;
  const _Float16* B = Bt + (size_t)bz * sB;

  const int gm0 = by * 256, gn0 = bx * 256;
  const int tid = threadIdx.x;
  const int lane = tid & 63, wave = tid >> 6;
  const int wm = (wave >> 2) * 128;
  const int wn = (wave & 3) * 64;
  const int fr = lane & 15, fq = lane >> 4;
  const int nkt = K >> 6;

  const int clog = ((tid & 7) ^ ((tid >> 3) & 7)) * 8;
  const _Float16* srcA = A + (size_t)(gm0 + (tid >> 3)) * K + clog;
  const _Float16* srcB = B + (size_t)(gn0 + (tid >> 3)) * K + clog;
  char* const dst0 = lds + tid * 16;

  auto SH = [&](int tile, int h) {
    const _Float16* s = (h < 2 ? srcA : srcB) + (size_t)((h & 1) * 128) * K
                        + tile * 64;
    char* d = dst0 + (tile & 1) * 65536 + h * 16384;
    gload_lds16(s, d);
    gload_lds16(s + (size_t)64 * K, d + 8192);
  };

  const int axor = fr & 7;
  const int pc0 = (fq ^ axor) * 16;
  const int pc1 = ((4 + fq) ^ axor) * 16;
  const int arb = (wm + fr) * 128;
  const int brb = 32768 + (wn + fr) * 128;

  f32x4 acc[8][4] = {};
  f16x8 af[4][2], b0[2][2], b1[2][2];

  SH(0, 0); SH(0, 1); SH(0, 2); SH(0, 3);
  if (nkt > 1) {
    SH(1, 0);
    asm volatile("s_waitcnt vmcnt(2)" ::: "memory");
  } else {
    asm volatile("s_waitcnt vmcnt(0)" ::: "memory");
  }
  __builtin_amdgcn_s_barrier();
  __builtin_amdgcn_sched_barrier(0);

#define PHASE_MID                                          \
  __builtin_amdgcn_s_barrier();                            \
  asm volatile("s_waitcnt lgkmcnt(0)" ::: "memory");       \
  __builtin_amdgcn_sched_barrier(0);                       \
  __builtin_amdgcn_s_setprio(1);
#define PHASE_END                                          \
  __builtin_amdgcn_s_setprio(0);                           \
  __builtin_amdgcn_sched_barrier(0);                       \
  __builtin_amdgcn_s_barrier();

  for (int t = 0; t < nkt; ++t) {
    const char* buf = lds + (t & 1) * 65536;
    const bool st1 = (t + 1) < nkt;

    #pragma unroll
    for (int mi = 0; mi < 4; ++mi) {
      af[mi][0] = *(const f16x8*)(buf + arb + mi * 2048 + pc0);
      af[mi][1] = *(const f16x8*)(buf + arb + mi * 2048 + pc1);
    }
    #pragma unroll
    for (int ni = 0; ni < 2; ++ni) {
      b0[ni][0] = *(const f16x8*)(buf + brb + ni * 2048 + pc0);
      b0[ni][1] = *(const f16x8*)(buf + brb + ni * 2048 + pc1);
    }
    if (st1) SH(t + 1, 1);
    PHASE_MID
    #pragma unroll
    for (int mi = 0; mi < 4; ++mi)
      #pragma unroll
      for (int ni = 0; ni < 2; ++ni)
        #pragma unroll
        for (int kk = 0; kk < 2; ++kk)
          acc[mi][ni] = MFMA16(af[mi][kk], b0[ni][kk], acc[mi][ni]);
    PHASE_END

    #pragma unroll
    for (int ni = 0; ni < 2; ++ni) {
      b1[ni][0] = *(const f16x8*)(buf + brb + (ni + 2) * 2048 + pc0);
      b1[ni][1] = *(const f16x8*)(buf + brb + (ni + 2) * 2048 + pc1);
    }
    if (st1) SH(t + 1, 2);
    PHASE_MID
    #pragma unroll
    for (int mi = 0; mi < 4; ++mi)
      #pragma unroll
      for (int ni = 0; ni < 2; ++ni)
        #pragma unroll
        for (int kk = 0; kk < 2; ++kk)
          acc[mi][ni + 2] = MFMA16(af[mi][kk], b1[ni][kk], acc[mi][ni + 2]);
    PHASE_END

    #pragma unroll
    for (int mi = 0; mi < 4; ++mi) {
      af[mi][0] = *(const f16x8*)(buf + arb + (mi + 4) * 2048 + pc0);
      af[mi][1] = *(const f16x8*)(buf + arb + (mi + 4) * 2048 + pc1);
    }
    if (st1) SH(t + 1, 3);
    PHASE_MID
    #pragma unroll
    for (int mi = 0; mi < 4; ++mi)
      #pragma unroll
      for (int ni = 0; ni < 2; ++ni)
        #pragma unroll
        for (int kk = 0; kk < 2; ++kk)
          acc[mi + 4][ni] = MFMA16(af[mi][kk], b0[ni][kk], acc[mi + 4][ni]);
    PHASE_END

    const bool st2 = (t + 2) < nkt;
    if (st2) SH(t + 2, 0);
    __builtin_amdgcn_s_barrier();
    __builtin_amdgcn_s_setprio(1);
    #pragma unroll
    for (int mi = 0; mi < 4; ++mi)
      #pragma unroll
      for (int ni = 0; ni < 2; ++ni)
        #pragma unroll
        for (int kk = 0; kk < 2; ++kk)
          acc[mi + 4][ni + 2] = MFMA16(af[mi][kk], b1[ni][kk], acc[mi + 4][ni + 2]);
    __builtin_amdgcn_s_setprio(0);
    __builtin_amdgcn_sched_barrier(0);
    if (st2) asm volatile("s_waitcnt vmcnt(2)" ::: "memory");
    else     asm volatile("s_waitcnt vmcnt(0)" ::: "memory");
    __builtin_amdgcn_s_barrier();
  }
#undef PHASE_MID
#undef PHASE_END

  const int erow = gm0 + wm + fq * 4;
  const int ecol = gn0 + wn + fr;
  #pragma unroll
  for (int m = 0; m < 8; ++m)
    #pragma unroll
    for (int n = 0; n < 4; ++n) {
      size_t base = (size_t)(erow + m * 16) * N + (ecol + n * 16);
      #pragma unroll
      for (int r = 0; r < 4; ++r) {
        float v = acc[m][n][r];
        if constexpr (MODE == 0)
          ((float*)Cv + (size_t)bz * sCz)[base + (size_t)r * N] = v * scale;
        else if constexpr (MODE == 1)
          ((_Float16*)Cv + (size_t)bz * sCz)[base + (size_t)r * N] = (_Float16)v;
        else
          ((_Float16*)Cv + (size_t)bz * sCz)[base + (size_t)r * N] =
              (_Float16)(v * scale);
      }
    }
}

// ---------------------------------------------------------------------------
// gemmO (r14 verbatim): 256x128, BK=32, 3-deep, 72KiB, 2 blocks/CU, lda/ldb.
// MODE 0: f32*scale ; 1: f16 ; 2: f16*scale.
template <int MODE>
__global__ __launch_bounds__(512, 4) void gemmO(
    const _Float16* __restrict__ At, size_t sAz, int lda,
    const _Float16* __restrict__ Bt, size_t sBz, int ldb,
    void* __restrict__ Cv, size_t sCz, int ldc,
    int K, float scale)
{
  extern __shared__ char lds[];
  int bx, by, bz;
  swz_block(bx, by, bz);
  const _Float16* A = At + (size_t)bz * sAz;
  const _Float16* B = Bt + (size_t)bz * sBz;

  const int gm0 = by * 256, gn0 = bx * 128;
  const int tid = threadIdx.x;
  const int lane = tid & 63, wave = tid >> 6;
  const int wm = (wave >> 1) * 64;
  const int wn = (wave & 1) * 64;
  const int fr = lane & 15, fq = lane >> 4;
  const int nkt = K >> 5;

  const int clog = ((tid & 3) ^ ((tid >> 3) & 3)) * 8;
  const _Float16* srcA = A + (size_t)(gm0 + (tid >> 2)) * lda + clog;
  const _Float16* srcB = B + (size_t)(gn0 + (tid >> 2)) * ldb + clog;
  char* const dst0 = lds + tid * 16;

  auto STG = [&](int tile) {
    const int off = tile * 32;
    char* d = dst0 + (tile % 3) * 24576;
    gload_lds16(srcA + off,                     d);
    gload_lds16(srcA + off + (size_t)128 * lda, d + 8192);
    gload_lds16(srcB + off,                     d + 16384);
  };

  const int pc  = (fq ^ ((fr >> 1) & 3)) * 16;
  const int arb = (wm + fr) * 64 + pc;
  const int brb = 16384 + (wn + fr) * 64 + pc;

  f32x4 acc[4][4] = {};
  f16x8 af[4], bfr[4];

  STG(0);
  if (nkt > 1) {
    STG(1);
    asm volatile("s_waitcnt vmcnt(3)" ::: "memory");
  } else {
    asm volatile("s_waitcnt vmcnt(0)" ::: "memory");
  }
  __builtin_amdgcn_s_barrier();
  __builtin_amdgcn_sched_barrier(0);

  for (int t = 0; t < nkt; ++t) {
    const char* buf = lds + (t % 3) * 24576;
    const bool st2 = (t + 2) < nkt;

    if (st2) STG(t + 2);

    #pragma unroll
    for (int mi = 0; mi < 4; ++mi)
      af[mi] = *(const f16x8*)(buf + arb + mi * 1024);
    #pragma unroll
    for (int ni = 0; ni < 4; ++ni)
      bfr[ni] = *(const f16x8*)(buf + brb + ni * 1024);

    __builtin_amdgcn_s_setprio(1);
    #pragma unroll
    for (int mi = 0; mi < 4; ++mi)
      #pragma unroll
      for (int ni = 0; ni < 4; ++ni)
        acc[mi][ni] = MFMA16(af[mi], bfr[ni], acc[mi][ni]);
    __builtin_amdgcn_s_setprio(0);

    if (st2)               asm volatile("s_waitcnt vmcnt(3)" ::: "memory");
    else if (t + 1 < nkt)  asm volatile("s_waitcnt vmcnt(0)" ::: "memory");
    __builtin_amdgcn_s_barrier();
    __builtin_amdgcn_sched_barrier(0);
  }

  const int erow = gm0 + wm + fq * 4;
  const int ecol = gn0 + wn + fr;
  #pragma unroll
  for (int m = 0; m < 4; ++m)
    #pragma unroll
    for (int n = 0; n < 4; ++n) {
      size_t base = (size_t)(erow + m * 16) * ldc + (ecol + n * 16);
      #pragma unroll
      for (int r = 0; r < 4; ++r) {
        float v = acc[m][n][r];
        size_t idx = base + (size_t)r * ldc;
        if constexpr (MODE == 0)
          ((float*)Cv + (size_t)bz * sCz)[idx] = v * scale;
        else if constexpr (MODE == 1)
          ((_Float16*)Cv + (size_t)bz * sCz)[idx] = (_Float16)v;
        else
          ((_Float16*)Cv + (size_t)bz * sCz)[idx] = (_Float16)(v * scale);
      }
    }
}

// ---------------------------------------------------------------------------
// Wave-per-row softmax: scores [8192 rows][2048] f16 -> P f16. 4 rows/block.
__global__ __launch_bounds__(256) void softmax_rows(
    const _Float16* __restrict__ S, _Float16* __restrict__ P)
{
  const int w = threadIdx.x >> 6, lane = threadIdx.x & 63;
  const size_t row = (size_t)blockIdx.x * 4 + w;
  const _Float16* sr = S + row * 2048;

  f16x8 v[4];
  #pragma unroll
  for (int c = 0; c < 4; ++c)
    v[c] = *(const f16x8*)(sr + c * 512 + lane * 8);

  float m = -1e30f;
  #pragma unroll
  for (int c = 0; c < 4; ++c)
    #pragma unroll
    for (int j = 0; j < 8; ++j) m = fmaxf(m, (float)v[c][j]);
  #pragma unroll
  for (int o = 32; o >= 1; o >>= 1) m = fmaxf(m, __shfl_xor(m, o));

  float e[4][8];
  float s = 0.f;
  #pragma unroll
  for (int c = 0; c < 4; ++c)
    #pragma unroll
    for (int j = 0; j < 8; ++j) {
      e[c][j] = __expf((float)v[c][j] - m);
      s += e[c][j];
    }
  #pragma unroll
  for (int o = 32; o >= 1; o >>= 1) s += __shfl_xor(s, o);

  const float inv = 1.0f / s;
  _Float16* pr = P + row * 2048;
  #pragma unroll
  for (int c = 0; c < 4; ++c) {
    f16x8 p;
    #pragma unroll
    for (int j = 0; j < 8; ++j) p[j] = (_Float16)(e[c][j] * inv);
    *(f16x8*)(pr + c * 512 + lane * 8) = p;
  }
}

// ---------------------------------------------------------------------------
extern "C" void kernel_launch(void* const* d_in, const int* in_sizes, int n_in,
                              void* d_out, int out_size, void* d_ws, size_t ws_size,
                              hipStream_t stream)
{
  const float* Xk = (const float*)d_in[0];
  const float* Xv = (const float*)d_in[1];
  const float* Xq = (const float*)d_in[2];
  const float* WK = (const float*)d_in[3];
  const float* WV = (const float*)d_in[4];
  const float* WQ = (const float*)d_in[5];
  float* out = (float*)d_out;
  char* ws = (char*)d_ws;

  _Float16* XF   = (_Float16*)(ws);               // 0..48 MiB (k,v,q)
  _Float16* WT   = (_Float16*)(ws + 48 * MiB);    // 48..54 (K,V,Q)
  _Float16* PROJ = (_Float16*)(ws + 54 * MiB);    // 54..86 (K,Q)
  _Float16* VTf  = (_Float16*)(ws + 86 * MiB);    // 86..102 [1024][8192]
  _Float16* SC   = (_Float16*)(ws + 102 * MiB);   // 102..134 (f16 scores)
  _Float16* P    = (_Float16*)(ws);               // alias XF_k+XF_v

  _Float16* Kp = PROJ;            // [8192][1024]
  _Float16* Qp = PROJ + MK;       // [8192][1024]

  auto* g1 = gemm8p<1>;
  auto* g2 = gemm8p<2>;
  auto* f1 = gemmO<1>;
  auto* f0 = gemmO<0>;
  (void)hipFuncSetAttribute((const void*)g1, hipFuncAttributeMaxDynamicSharedMemorySize, 131072);
  (void)hipFuncSetAttribute((const void*)g2, hipFuncAttributeMaxDynamicSharedMemorySize, 131072);
  (void)hipFuncSetAttribute((const void*)f1, hipFuncAttributeMaxDynamicSharedMemorySize, 73728);
  (void)hipFuncSetAttribute((const void*)f0, hipFuncAttributeMaxDynamicSharedMemorySize, 73728);

  // 1) prep: X -> f16 (16 floats/thread) + W -> W^T f16
  prep<<<dim3(9216), 256, 0, stream>>>(Xk, Xv, Xq, XF, WK, WV, WQ, WT);
  // 2) K,Q projections on gemm8p: (4,32,2) = 256 blocks = 1.0 round
  //    z=0: XF_k @ WT_K^T -> Kp ; z=1: XF_q @ WT_Q^T -> Qp
  gemm8p<1><<<dim3(4, 32, 2), 512, 131072, stream>>>(
      XF, 2 * MK, WT, 2 * WSZ, PROJ, MK, 1024, 1024, 1.0f);
  // 3) V^T projection: VTf[e][s_glob] = sum_k WT_V[e][k] * XF_v[s][k]
  //    M=1024, N=8192 -> 256 blocks = 1 round
  gemmO<1><<<dim3(64, 4, 1), 512, 73728, stream>>>(
      WT + WSZ, 0, 1024, XF + MK, 0, 1024,
      VTf, 0, 8192, 1024, 1.0f);
  // 4) scores on gemm8p: (8,8,4) = 256 blocks = 1.0 round
  gemm8p<2><<<dim3(8, 8, 4), 512, 131072, stream>>>(
      Qp, (size_t)2048 * 1024, Kp, (size_t)2048 * 1024,
      SC, (size_t)2048 * 2048, 2048, 1024, 0.022097086912079608f);
  // 5) softmax (wave-per-row) -> P f16
  softmax_rows<<<dim3(2048), 256, 0, stream>>>(SC, P);
  // 6) out[b] = P[b] @ V[b]: C[m][e] = sum_k P[m][k] * VTf[e][b*2048+k]
  gemmO<0><<<dim3(8, 8, 4), 512, 73728, stream>>>(
      P, (size_t)2048 * 2048, 2048, VTf, 2048, 8192,
      out, (size_t)2048 * 1024, 1024, 2048, 1.0f);
}